// Round 1
// baseline (969.055 us; speedup 1.0000x reference)
//
#include <hip/hip_runtime.h>
#include <hip/hip_bf16.h>
#include <cstdint>

// Problem constants
#define NB     16384   // batch
#define DIN    1024
#define HID    2048
#define NE     8
#define NC     8
#define DZ     256

// Main GEMM tiling
#define BM     128     // hidden rows per chunk
#define BNB    128     // batch cols per tile
#define BK     32
#define NCHUNK (HID/BM)    // 16
#define KSTEPS (DIN/BK)    // 32

typedef short bf16x8 __attribute__((ext_vector_type(8)));
typedef float f32x4  __attribute__((ext_vector_type(4)));

__device__ __forceinline__ unsigned short f2bf(float f) {
    unsigned int u = __float_as_uint(f);
    unsigned int r = (u + 0x7FFFu + ((u >> 16) & 1u)) >> 16;
    return (unsigned short)r;
}

__device__ __forceinline__ void async_copy16(const void* g, void* l) {
    __builtin_amdgcn_global_load_lds(
        (const __attribute__((address_space(1))) unsigned int*)g,
        (__attribute__((address_space(3))) unsigned int*)l, 16, 0, 0);
}

// ---------------------------------------------------------------------------
// Gate: w = softmax(cos_sim(z, mu)/tau). One wave per row. Also zeroes logits.
// ---------------------------------------------------------------------------
__global__ __launch_bounds__(256) void k_gate(const float* __restrict__ z,
                                              const float* __restrict__ mu,
                                              const int* __restrict__ tau_i,
                                              float* __restrict__ wout,
                                              float* __restrict__ logits) {
    int row = blockIdx.x * 4 + (threadIdx.x >> 6);
    int l = threadIdx.x & 63;
    float4 zv = *(const float4*)&z[(size_t)row * DZ + l * 4];
    float zz = zv.x * zv.x + zv.y * zv.y + zv.z * zv.z + zv.w * zv.w;
    float dots[NE], mm[NE];
#pragma unroll
    for (int e = 0; e < NE; ++e) {
        float4 m = *(const float4*)&mu[e * DZ + l * 4];
        dots[e] = zv.x * m.x + zv.y * m.y + zv.z * m.z + zv.w * m.w;
        mm[e]   = m.x * m.x + m.y * m.y + m.z * m.z + m.w * m.w;
    }
#pragma unroll
    for (int off = 32; off; off >>= 1) {
        zz += __shfl_xor(zz, off);
#pragma unroll
        for (int e = 0; e < NE; ++e) {
            dots[e] += __shfl_xor(dots[e], off);
            mm[e]   += __shfl_xor(mm[e], off);
        }
    }
    float zn = fmaxf(sqrtf(zz), 1e-12f);
    float tau = fmaxf(1e-6f, (float)tau_i[0]);
    float s[NE], mx = -1e30f;
#pragma unroll
    for (int e = 0; e < NE; ++e) {
        s[e] = dots[e] / (zn * fmaxf(sqrtf(mm[e]), 1e-12f)) / tau;
        mx = fmaxf(mx, s[e]);
    }
    float sum = 0.f;
#pragma unroll
    for (int e = 0; e < NE; ++e) { s[e] = expf(s[e] - mx); sum += s[e]; }
    float inv = 1.f / sum;
    if (l < NE) {
        wout[(size_t)row * NE + l]   = s[l] * inv;
        logits[(size_t)row * NE + l] = 0.f;   // zero-init for atomics
    }
}

// ---------------------------------------------------------------------------
// LayerNorm (shared part) -> bf16 xhat. One block per row.
// ---------------------------------------------------------------------------
__global__ __launch_bounds__(256) void k_ln(const float* __restrict__ feat,
                                            unsigned short* __restrict__ xhat) {
    int row = blockIdx.x;
    int t = threadIdx.x;
    float4 v = *(const float4*)&feat[(size_t)row * DIN + t * 4];
    float s  = v.x + v.y + v.z + v.w;
    float sq = v.x * v.x + v.y * v.y + v.z * v.z + v.w * v.w;
#pragma unroll
    for (int off = 32; off; off >>= 1) {
        s  += __shfl_down(s, off);
        sq += __shfl_down(sq, off);
    }
    __shared__ float ls[8];
    int w = t >> 6, l = t & 63;
    if (l == 0) { ls[w] = s; ls[4 + w] = sq; }
    __syncthreads();
    s  = ls[0] + ls[1] + ls[2] + ls[3];
    sq = ls[4] + ls[5] + ls[6] + ls[7];
    float mean = s * (1.f / DIN);
    float var  = sq * (1.f / DIN) - mean * mean;
    float r = 1.0f / sqrtf(var + 1e-5f);
    uint2 p;
    p.x = (unsigned)f2bf((v.x - mean) * r) | ((unsigned)f2bf((v.y - mean) * r) << 16);
    p.y = (unsigned)f2bf((v.z - mean) * r) | ((unsigned)f2bf((v.w - mean) * r) << 16);
    *(uint2*)&xhat[(size_t)row * DIN + t * 4] = p;
}

// ---------------------------------------------------------------------------
// W2 transpose->bf16 (padded [E][16][HID]) and b1p init (copy of b1).
// ---------------------------------------------------------------------------
__global__ __launch_bounds__(256) void k_w2prep(const float* __restrict__ W2,
                                                const float* __restrict__ b1,
                                                unsigned short* __restrict__ w2t,
                                                float* __restrict__ b1p) {
    int i = blockIdx.x * 256 + threadIdx.x;   // 8*16*2048 = 262144
    int e = i >> 15;
    int rem = i & 32767;
    int c = rem >> 11;
    int h = rem & 2047;
    float v = (c < NC) ? W2[((size_t)(e * HID + h)) * NC + c] : 0.f;
    w2t[i] = f2bf(v);
    if (i < NE * HID) b1p[i] = b1[i];
}

// ---------------------------------------------------------------------------
// W1 fold+transpose: W1t[e][h][d] = bf16(gamma[e][d] * W1[e][d][h]);
// b1p[e][h] += sum_d beta[e][d]*W1[e][d][h].  64x64 LDS tile transpose.
// ---------------------------------------------------------------------------
__global__ __launch_bounds__(256) void k_w1prep(const float* __restrict__ W1,
                                                const float* __restrict__ gamma,
                                                const float* __restrict__ beta,
                                                unsigned short* __restrict__ w1t,
                                                float* __restrict__ b1p) {
    __shared__ float tile[64][65];   // [h-local][d-local], unscaled
    int e  = blockIdx.z;
    int d0 = blockIdx.y * 64;
    int h0 = blockIdx.x * 64;
    int tx = threadIdx.x & 15, ty = threadIdx.x >> 4;
#pragma unroll
    for (int rr = 0; rr < 4; ++rr) {
        int d = ty + rr * 16;
        float4 v = *(const float4*)&W1[((size_t)e * DIN + d0 + d) * HID + h0 + tx * 4];
        tile[tx * 4 + 0][d] = v.x;
        tile[tx * 4 + 1][d] = v.y;
        tile[tx * 4 + 2][d] = v.z;
        tile[tx * 4 + 3][d] = v.w;
    }
    __syncthreads();
    float4 g = *(const float4*)&gamma[(size_t)e * DIN + d0 + tx * 4];
#pragma unroll
    for (int rr = 0; rr < 4; ++rr) {
        int h = ty + rr * 16;
        uint2 p;
        p.x = (unsigned)f2bf(tile[h][tx * 4 + 0] * g.x) |
              ((unsigned)f2bf(tile[h][tx * 4 + 1] * g.y) << 16);
        p.y = (unsigned)f2bf(tile[h][tx * 4 + 2] * g.z) |
              ((unsigned)f2bf(tile[h][tx * 4 + 3] * g.w) << 16);
        *(uint2*)&w1t[((size_t)e * HID + h0 + h) * DIN + d0 + tx * 4] = p;
    }
    if (threadIdx.x < 64) {
        int h = threadIdx.x;
        float sacc = 0.f;
        for (int r = 0; r < 64; ++r)
            sacc += beta[(size_t)e * DIN + d0 + r] * tile[h][r];
        atomicAdd(&b1p[(size_t)e * HID + h0 + h], sacc);
    }
}

// ---------------------------------------------------------------------------
// Fused main kernel: per (btile, e) computes hT = W1t[e] @ xhat^T chunk by
// chunk (128 hid x 128 b, K=1024), fuses bias+relu, and feeds the second
// GEMM (h @ W2) via per-wave LDS round-trip; acc2 persists across chunks.
// Finishes with w[b,e]*(d2 + b2) atomicAdd into logits.
// ---------------------------------------------------------------------------
__global__ __launch_bounds__(256, 2) void moe_main(
        const unsigned short* __restrict__ xhat,   // [B][DIN] bf16
        const unsigned short* __restrict__ w1t,    // [E][HID][DIN] bf16
        const float* __restrict__ b1p,             // [E][HID]
        const unsigned short* __restrict__ w2t,    // [E][16][HID] bf16 (c>=8 zero)
        const float* __restrict__ b2,              // [E][NC]
        const float* __restrict__ wg,              // [B][NE]
        float* __restrict__ logits) {              // [B][NC]
    __shared__ __align__(16) short lds_a[BM * BK];     // 8 KB, [hid 128][k 32]
    __shared__ __align__(16) short lds_b[BNB * BK];    // 8 KB, [b 128][k 32]
    __shared__ __align__(16) char  lds_ht[4 * 64 * 144];  // 36 KB per-wave hT

    const int t = threadIdx.x;
    const int w = t >> 6, l = t & 63;
    const int q = l >> 4, ml = l & 15;
    const int flat = blockIdx.x;
    const int e = flat & 7;           // e-inner for L2 sharing of xhat tiles
    const int btile = flat >> 3;
    const int b0 = btile * BNB;
    const int wm = (w >> 1) * 64;     // wave's hid-half
    const int wn = (w & 1) * 64;      // wave's b-half

    const int ldrow  = w * 16 + (l >> 2);   // staging row within 64-row half
    const int kslot8 = (l & 3) * 8;         // staging k-offset (elems)
    const unsigned short* gA = w1t + (size_t)e * HID * DIN;
    const unsigned short* gB = xhat + (size_t)b0 * DIN;
    char* myht = lds_ht + w * 9216;         // 64 rows(b) x 144 B

    f32x4 acc2[4];
#pragma unroll
    for (int tb = 0; tb < 4; ++tb) acc2[tb] = (f32x4){0.f, 0.f, 0.f, 0.f};

    for (int ch = 0; ch < NCHUNK; ++ch) {
        const int hid0 = ch * BM;
        f32x4 acc[4][4];
#pragma unroll
        for (int i = 0; i < 4; ++i)
#pragma unroll
            for (int j = 0; j < 4; ++j) acc[i][j] = (f32x4){0.f, 0.f, 0.f, 0.f};

        for (int ks = 0; ks < KSTEPS; ++ks) {
            const int k0 = ks * BK;
#pragma unroll
            for (int it = 0; it < 2; ++it) {
                const int row = it * 64 + ldrow;
                async_copy16(gA + (size_t)(hid0 + row) * DIN + k0 + kslot8,
                             (char*)lds_a + it * 4096 + w * 1024 + (l << 4));
                async_copy16(gB + (size_t)row * DIN + k0 + kslot8,
                             (char*)lds_b + it * 4096 + w * 1024 + (l << 4));
            }
            __syncthreads();   // drains vmcnt before barrier (m97 pattern)
            bf16x8 aF[4], bF[4];
#pragma unroll
            for (int i = 0; i < 4; ++i)
                aF[i] = *(const bf16x8*)&lds_a[(wm + 16 * i + ml) * BK + q * 8];
#pragma unroll
            for (int j = 0; j < 4; ++j)
                bF[j] = *(const bf16x8*)&lds_b[(wn + 16 * j + ml) * BK + q * 8];
#pragma unroll
            for (int i = 0; i < 4; ++i)
#pragma unroll
                for (int j = 0; j < 4; ++j)
                    acc[i][j] = __builtin_amdgcn_mfma_f32_16x16x32_bf16(
                        aF[i], bF[j], acc[i][j], 0, 0, 0);
            __syncthreads();   // all waves done reading before next stage
        }

        // ---- chunk epilogue: bias+relu -> bf16 -> per-wave LDS [b][hid] ----
#pragma unroll
        for (int i = 0; i < 4; ++i) {
            const float4 bias =
                *(const float4*)&b1p[(size_t)e * HID + ch * BM + wm + 16 * i + 4 * q];
#pragma unroll
            for (int j = 0; j < 4; ++j) {
                float v0 = fmaxf(acc[i][j].x + bias.x, 0.f);
                float v1 = fmaxf(acc[i][j].y + bias.y, 0.f);
                float v2 = fmaxf(acc[i][j].z + bias.z, 0.f);
                float v3 = fmaxf(acc[i][j].w + bias.w, 0.f);
                uint2 p;
                p.x = (unsigned)f2bf(v0) | ((unsigned)f2bf(v1) << 16);
                p.y = (unsigned)f2bf(v2) | ((unsigned)f2bf(v3) << 16);
                const int brow = 16 * j + ml;   // local b in wave (0..63)
                *(uint2*)(myht + brow * 144 + (16 * i + 4 * q) * 2) = p;
            }
        }
        // ---- second GEMM: acc2 += hT_chunk @ W2 (wave-private, no barrier) ----
#pragma unroll
        for (int s = 0; s < 2; ++s) {
            const bf16x8 b2f = *(const bf16x8*)&w2t[((size_t)e * 16 + ml) * HID +
                                                    ch * BM + wm + 32 * s + 8 * q];
#pragma unroll
            for (int tb = 0; tb < 4; ++tb) {
                const bf16x8 a2f =
                    *(const bf16x8*)(myht + (16 * tb + ml) * 144 + (32 * s + 8 * q) * 2);
                acc2[tb] = __builtin_amdgcn_mfma_f32_16x16x32_bf16(
                    a2f, b2f, acc2[tb], 0, 0, 0);
            }
        }
    }

    // ---- cross-wave (hid-half) reduction of acc2, then gated atomic store ----
    __syncthreads();
    float* red = (float*)lds_ht;
    if (w >= 2) {
        float* dst = red + ((size_t)((w & 1) * 64 + l)) * 16;
#pragma unroll
        for (int tb = 0; tb < 4; ++tb)
#pragma unroll
            for (int r = 0; r < 4; ++r) dst[tb * 4 + r] = acc2[tb][r];
    }
    __syncthreads();
    if (w < 2) {
        const float* src = red + ((size_t)((w & 1) * 64 + l)) * 16;
        const int c = ml;   // D2 col = lane&15
        if (c < NC) {
            const float b2v = b2[e * NC + c];
#pragma unroll
            for (int tb = 0; tb < 4; ++tb) {
#pragma unroll
                for (int r = 0; r < 4; ++r) {
                    float v = acc2[tb][r] + src[tb * 4 + r];
                    const int bg = b0 + wn + 16 * tb + 4 * q + r;
                    const float wgt = wg[(size_t)bg * NE + e];
                    atomicAdd(&logits[(size_t)bg * NC + c], wgt * (v + b2v));
                }
            }
        }
    }
}

// ---------------------------------------------------------------------------
extern "C" void kernel_launch(void* const* d_in, const int* in_sizes, int n_in,
                              void* d_out, int out_size, void* d_ws, size_t ws_size,
                              hipStream_t stream) {
    const float* feat  = (const float*)d_in[0];
    const float* z     = (const float*)d_in[1];
    const float* mu    = (const float*)d_in[2];
    const float* gamma = (const float*)d_in[3];
    const float* beta  = (const float*)d_in[4];
    const float* W1    = (const float*)d_in[5];
    const float* b1    = (const float*)d_in[6];
    const float* W2    = (const float*)d_in[7];
    const float* b2    = (const float*)d_in[8];
    const int*   tau   = (const int*)d_in[9];

    float* logits = (float*)d_out;                 // [B][NC]
    float* wout   = logits + (size_t)NB * NC;      // [B][NE]

    char* ws = (char*)d_ws;
    unsigned short* xhat = (unsigned short*)ws;                       // 33.5 MB
    unsigned short* w1t  = (unsigned short*)(ws + 33554432);          // 33.5 MB
    unsigned short* w2t  = (unsigned short*)(ws + 67108864);          // 0.5 MB
    float*          b1p  = (float*)(ws + 67633152);                   // 64 KB

    k_gate<<<NB / 4, 256, 0, stream>>>(z, mu, tau, wout, logits);
    k_ln<<<NB, 256, 0, stream>>>(feat, xhat);
    k_w2prep<<<(NE * 16 * HID) / 256, 256, 0, stream>>>(W2, b1, w2t, b1p);
    k_w1prep<<<dim3(HID / 64, DIN / 64, NE), 256, 0, stream>>>(W1, gamma, beta, w1t, b1p);
    moe_main<<<dim3((NB / BNB) * NE), 256, 0, stream>>>(xhat, w1t, b1p, w2t, b2,
                                                        wout, logits);
}

// Round 2
// 943.537 us; speedup vs baseline: 1.0270x; 1.0270x over previous
//
#include <hip/hip_runtime.h>
#include <hip/hip_bf16.h>
#include <cstdint>

// Problem constants
#define NB     16384   // batch
#define DIN    1024
#define HID    2048
#define NE     8
#define NC     8
#define DZ     256

// Main GEMM tiling
#define BM     128     // hidden rows per chunk
#define BNB    128     // batch cols per tile
#define BK     32
#define NCHUNK (HID/BM)    // 16
#define KSTEPS (DIN/BK)    // 32

typedef short bf16x8 __attribute__((ext_vector_type(8)));
typedef float f32x4  __attribute__((ext_vector_type(4)));

__device__ __forceinline__ unsigned short f2bf(float f) {
    unsigned int u = __float_as_uint(f);
    unsigned int r = (u + 0x7FFFu + ((u >> 16) & 1u)) >> 16;
    return (unsigned short)r;
}

__device__ __forceinline__ void async_copy16(const void* g, void* l) {
    __builtin_amdgcn_global_load_lds(
        (const __attribute__((address_space(1))) unsigned int*)g,
        (__attribute__((address_space(3))) unsigned int*)l, 16, 0, 0);
}

// ---------------------------------------------------------------------------
// Gate: w = softmax(cos_sim(z, mu)/tau). One wave per row. Also zeroes logits.
// ---------------------------------------------------------------------------
__global__ __launch_bounds__(256) void k_gate(const float* __restrict__ z,
                                              const float* __restrict__ mu,
                                              const int* __restrict__ tau_i,
                                              float* __restrict__ wout,
                                              float* __restrict__ logits) {
    int row = blockIdx.x * 4 + (threadIdx.x >> 6);
    int l = threadIdx.x & 63;
    float4 zv = *(const float4*)&z[(size_t)row * DZ + l * 4];
    float zz = zv.x * zv.x + zv.y * zv.y + zv.z * zv.z + zv.w * zv.w;
    float dots[NE], mm[NE];
#pragma unroll
    for (int e = 0; e < NE; ++e) {
        float4 m = *(const float4*)&mu[e * DZ + l * 4];
        dots[e] = zv.x * m.x + zv.y * m.y + zv.z * m.z + zv.w * m.w;
        mm[e]   = m.x * m.x + m.y * m.y + m.z * m.z + m.w * m.w;
    }
#pragma unroll
    for (int off = 32; off; off >>= 1) {
        zz += __shfl_xor(zz, off);
#pragma unroll
        for (int e = 0; e < NE; ++e) {
            dots[e] += __shfl_xor(dots[e], off);
            mm[e]   += __shfl_xor(mm[e], off);
        }
    }
    float zn = fmaxf(sqrtf(zz), 1e-12f);
    float tau = fmaxf(1e-6f, (float)tau_i[0]);
    float s[NE], mx = -1e30f;
#pragma unroll
    for (int e = 0; e < NE; ++e) {
        s[e] = dots[e] / (zn * fmaxf(sqrtf(mm[e]), 1e-12f)) / tau;
        mx = fmaxf(mx, s[e]);
    }
    float sum = 0.f;
#pragma unroll
    for (int e = 0; e < NE; ++e) { s[e] = expf(s[e] - mx); sum += s[e]; }
    float inv = 1.f / sum;
    if (l < NE) {
        wout[(size_t)row * NE + l]   = s[l] * inv;
        logits[(size_t)row * NE + l] = 0.f;   // zero-init for atomics
    }
}

// ---------------------------------------------------------------------------
// LayerNorm (shared part) -> bf16 xhat. One block per row.
// ---------------------------------------------------------------------------
__global__ __launch_bounds__(256) void k_ln(const float* __restrict__ feat,
                                            unsigned short* __restrict__ xhat) {
    int row = blockIdx.x;
    int t = threadIdx.x;
    float4 v = *(const float4*)&feat[(size_t)row * DIN + t * 4];
    float s  = v.x + v.y + v.z + v.w;
    float sq = v.x * v.x + v.y * v.y + v.z * v.z + v.w * v.w;
#pragma unroll
    for (int off = 32; off; off >>= 1) {
        s  += __shfl_down(s, off);
        sq += __shfl_down(sq, off);
    }
    __shared__ float ls[8];
    int w = t >> 6, l = t & 63;
    if (l == 0) { ls[w] = s; ls[4 + w] = sq; }
    __syncthreads();
    s  = ls[0] + ls[1] + ls[2] + ls[3];
    sq = ls[4] + ls[5] + ls[6] + ls[7];
    float mean = s * (1.f / DIN);
    float var  = sq * (1.f / DIN) - mean * mean;
    float r = 1.0f / sqrtf(var + 1e-5f);
    uint2 p;
    p.x = (unsigned)f2bf((v.x - mean) * r) | ((unsigned)f2bf((v.y - mean) * r) << 16);
    p.y = (unsigned)f2bf((v.z - mean) * r) | ((unsigned)f2bf((v.w - mean) * r) << 16);
    *(uint2*)&xhat[(size_t)row * DIN + t * 4] = p;
}

// ---------------------------------------------------------------------------
// W2 transpose->bf16 (padded [E][16][HID]) and b1p init (copy of b1).
// ---------------------------------------------------------------------------
__global__ __launch_bounds__(256) void k_w2prep(const float* __restrict__ W2,
                                                const float* __restrict__ b1,
                                                unsigned short* __restrict__ w2t,
                                                float* __restrict__ b1p) {
    int i = blockIdx.x * 256 + threadIdx.x;   // 8*16*2048 = 262144
    int e = i >> 15;
    int rem = i & 32767;
    int c = rem >> 11;
    int h = rem & 2047;
    float v = (c < NC) ? W2[((size_t)(e * HID + h)) * NC + c] : 0.f;
    w2t[i] = f2bf(v);
    if (i < NE * HID) b1p[i] = b1[i];
}

// ---------------------------------------------------------------------------
// W1 fold+transpose: W1t[e][h][d] = bf16(gamma[e][d] * W1[e][d][h]);
// b1p[e][h] += sum_d beta[e][d]*W1[e][d][h].  64x64 LDS tile transpose.
// ---------------------------------------------------------------------------
__global__ __launch_bounds__(256) void k_w1prep(const float* __restrict__ W1,
                                                const float* __restrict__ gamma,
                                                const float* __restrict__ beta,
                                                unsigned short* __restrict__ w1t,
                                                float* __restrict__ b1p) {
    __shared__ float tile[64][65];   // [h-local][d-local], unscaled
    int e  = blockIdx.z;
    int d0 = blockIdx.y * 64;
    int h0 = blockIdx.x * 64;
    int tx = threadIdx.x & 15, ty = threadIdx.x >> 4;
#pragma unroll
    for (int rr = 0; rr < 4; ++rr) {
        int d = ty + rr * 16;
        float4 v = *(const float4*)&W1[((size_t)e * DIN + d0 + d) * HID + h0 + tx * 4];
        tile[tx * 4 + 0][d] = v.x;
        tile[tx * 4 + 1][d] = v.y;
        tile[tx * 4 + 2][d] = v.z;
        tile[tx * 4 + 3][d] = v.w;
    }
    __syncthreads();
    float4 g = *(const float4*)&gamma[(size_t)e * DIN + d0 + tx * 4];
#pragma unroll
    for (int rr = 0; rr < 4; ++rr) {
        int h = ty + rr * 16;
        uint2 p;
        p.x = (unsigned)f2bf(tile[h][tx * 4 + 0] * g.x) |
              ((unsigned)f2bf(tile[h][tx * 4 + 1] * g.y) << 16);
        p.y = (unsigned)f2bf(tile[h][tx * 4 + 2] * g.z) |
              ((unsigned)f2bf(tile[h][tx * 4 + 3] * g.w) << 16);
        *(uint2*)&w1t[((size_t)e * HID + h0 + h) * DIN + d0 + tx * 4] = p;
    }
    if (threadIdx.x < 64) {
        int h = threadIdx.x;
        float sacc = 0.f;
        for (int r = 0; r < 64; ++r)
            sacc += beta[(size_t)e * DIN + d0 + r] * tile[h][r];
        atomicAdd(&b1p[(size_t)e * HID + h0 + h], sacc);
    }
}

// ---------------------------------------------------------------------------
// Fused main kernel. LDS staging uses a XOR-swizzled [row][k-chunk] layout:
// 16B chunk c of row r lives at physical chunk (c ^ ((r>>1)&3)). This makes
// the fragment ds_read_b128 conflict-free (8 bank-quads x 2 lanes per
// 16-lane phase = 2-way aggregate, the wave64 floor) while keeping the
// global_load_lds fetch perfectly coalesced (only permutes 16B pieces
// within each 64B line). R0 measured 7.4e7 conflict cycles from the
// unswizzled layout (~4.4 cyc extra per read).
// ---------------------------------------------------------------------------
__global__ __launch_bounds__(256, 3) void moe_main(
        const unsigned short* __restrict__ xhat,   // [B][DIN] bf16
        const unsigned short* __restrict__ w1t,    // [E][HID][DIN] bf16
        const float* __restrict__ b1p,             // [E][HID]
        const unsigned short* __restrict__ w2t,    // [E][16][HID] bf16 (c>=8 zero)
        const float* __restrict__ b2,              // [E][NC]
        const float* __restrict__ wg,              // [B][NE]
        float* __restrict__ logits) {              // [B][NC]
    __shared__ __align__(16) short lds_a[BM * BK];     // 8 KB, swizzled
    __shared__ __align__(16) short lds_b[BNB * BK];    // 8 KB, swizzled
    __shared__ __align__(16) char  lds_ht[4 * 64 * 144];  // 36 KB per-wave hT

    const int t = threadIdx.x;
    const int w = t >> 6, l = t & 63;
    const int q = l >> 4, ml = l & 15;
    const int flat = blockIdx.x;
    const int e = flat & 7;           // e-inner for L2 sharing of xhat tiles
    const int btile = flat >> 3;
    const int b0 = btile * BNB;
    const int wm = (w >> 1) * 64;     // wave's hid-half
    const int wn = (w & 1) * 64;      // wave's b-half

    const int ldrow  = w * 16 + (l >> 2);              // staging row in 64-half
    const int kslot8 = (((l & 3) ^ ((l >> 3) & 3))) * 8;  // swizzled k-chunk
    const int swz8   = (q ^ ((ml >> 1) & 3)) * 8;      // read-side swizzle
    const unsigned short* gA = w1t + (size_t)e * HID * DIN;
    const unsigned short* gB = xhat + (size_t)b0 * DIN;
    char* myht = lds_ht + w * 9216;         // 64 rows(b) x 144 B

    f32x4 acc2[4];
#pragma unroll
    for (int tb = 0; tb < 4; ++tb) acc2[tb] = (f32x4){0.f, 0.f, 0.f, 0.f};

    for (int ch = 0; ch < NCHUNK; ++ch) {
        const int hid0 = ch * BM;
        f32x4 acc[4][4];
#pragma unroll
        for (int i = 0; i < 4; ++i)
#pragma unroll
            for (int j = 0; j < 4; ++j) acc[i][j] = (f32x4){0.f, 0.f, 0.f, 0.f};

        for (int ks = 0; ks < KSTEPS; ++ks) {
            const int k0 = ks * BK;
#pragma unroll
            for (int it = 0; it < 2; ++it) {
                const int row = it * 64 + ldrow;
                async_copy16(gA + (size_t)(hid0 + row) * DIN + k0 + kslot8,
                             (char*)lds_a + it * 4096 + w * 1024 + (l << 4));
                async_copy16(gB + (size_t)row * DIN + k0 + kslot8,
                             (char*)lds_b + it * 4096 + w * 1024 + (l << 4));
            }
            __syncthreads();   // drains vmcnt before barrier (m97 pattern)
            bf16x8 aF[4], bF[4];
#pragma unroll
            for (int i = 0; i < 4; ++i)
                aF[i] = *(const bf16x8*)&lds_a[(wm + 16 * i + ml) * BK + swz8];
#pragma unroll
            for (int j = 0; j < 4; ++j)
                bF[j] = *(const bf16x8*)&lds_b[(wn + 16 * j + ml) * BK + swz8];
#pragma unroll
            for (int i = 0; i < 4; ++i)
#pragma unroll
                for (int j = 0; j < 4; ++j)
                    acc[i][j] = __builtin_amdgcn_mfma_f32_16x16x32_bf16(
                        aF[i], bF[j], acc[i][j], 0, 0, 0);
            __syncthreads();   // all waves done reading before next stage
        }

        // ---- chunk epilogue: bias+relu -> bf16 -> per-wave LDS [b][hid] ----
#pragma unroll
        for (int i = 0; i < 4; ++i) {
            const float4 bias =
                *(const float4*)&b1p[(size_t)e * HID + ch * BM + wm + 16 * i + 4 * q];
#pragma unroll
            for (int j = 0; j < 4; ++j) {
                float v0 = fmaxf(acc[i][j].x + bias.x, 0.f);
                float v1 = fmaxf(acc[i][j].y + bias.y, 0.f);
                float v2 = fmaxf(acc[i][j].z + bias.z, 0.f);
                float v3 = fmaxf(acc[i][j].w + bias.w, 0.f);
                uint2 p;
                p.x = (unsigned)f2bf(v0) | ((unsigned)f2bf(v1) << 16);
                p.y = (unsigned)f2bf(v2) | ((unsigned)f2bf(v3) << 16);
                const int brow = 16 * j + ml;   // local b in wave (0..63)
                *(uint2*)(myht + brow * 144 + (16 * i + 4 * q) * 2) = p;
            }
        }
        // ---- second GEMM: acc2 += hT_chunk @ W2 (wave-private, no barrier) ----
#pragma unroll
        for (int s = 0; s < 2; ++s) {
            const bf16x8 b2f = *(const bf16x8*)&w2t[((size_t)e * 16 + ml) * HID +
                                                    ch * BM + wm + 32 * s + 8 * q];
#pragma unroll
            for (int tb = 0; tb < 4; ++tb) {
                const bf16x8 a2f =
                    *(const bf16x8*)(myht + (16 * tb + ml) * 144 + (32 * s + 8 * q) * 2);
                acc2[tb] = __builtin_amdgcn_mfma_f32_16x16x32_bf16(
                    a2f, b2f, acc2[tb], 0, 0, 0);
            }
        }
    }

    // ---- cross-wave (hid-half) reduction of acc2, then gated atomic store ----
    __syncthreads();
    float* red = (float*)lds_ht;
    if (w >= 2) {
        float* dst = red + ((size_t)((w & 1) * 64 + l)) * 16;
#pragma unroll
        for (int tb = 0; tb < 4; ++tb)
#pragma unroll
            for (int r = 0; r < 4; ++r) dst[tb * 4 + r] = acc2[tb][r];
    }
    __syncthreads();
    if (w < 2) {
        const float* src = red + ((size_t)((w & 1) * 64 + l)) * 16;
        const int c = ml;   // D2 col = lane&15
        if (c < NC) {
            const float b2v = b2[e * NC + c];
#pragma unroll
            for (int tb = 0; tb < 4; ++tb) {
#pragma unroll
                for (int r = 0; r < 4; ++r) {
                    float v = acc2[tb][r] + src[tb * 4 + r];
                    const int bg = b0 + wn + 16 * tb + 4 * q + r;
                    const float wgt = wg[(size_t)bg * NE + e];
                    atomicAdd(&logits[(size_t)bg * NC + c], wgt * (v + b2v));
                }
            }
        }
    }
}

// ---------------------------------------------------------------------------
extern "C" void kernel_launch(void* const* d_in, const int* in_sizes, int n_in,
                              void* d_out, int out_size, void* d_ws, size_t ws_size,
                              hipStream_t stream) {
    const float* feat  = (const float*)d_in[0];
    const float* z     = (const float*)d_in[1];
    const float* mu    = (const float*)d_in[2];
    const float* gamma = (const float*)d_in[3];
    const float* beta  = (const float*)d_in[4];
    const float* W1    = (const float*)d_in[5];
    const float* b1    = (const float*)d_in[6];
    const float* W2    = (const float*)d_in[7];
    const float* b2    = (const float*)d_in[8];
    const int*   tau   = (const int*)d_in[9];

    float* logits = (float*)d_out;                 // [B][NC]
    float* wout   = logits + (size_t)NB * NC;      // [B][NE]

    char* ws = (char*)d_ws;
    unsigned short* xhat = (unsigned short*)ws;                       // 33.5 MB
    unsigned short* w1t  = (unsigned short*)(ws + 33554432);          // 33.5 MB
    unsigned short* w2t  = (unsigned short*)(ws + 67108864);          // 0.5 MB
    float*          b1p  = (float*)(ws + 67633152);                   // 64 KB

    k_gate<<<NB / 4, 256, 0, stream>>>(z, mu, tau, wout, logits);
    k_ln<<<NB, 256, 0, stream>>>(feat, xhat);
    k_w2prep<<<(NE * 16 * HID) / 256, 256, 0, stream>>>(W2, b1, w2t, b1p);
    k_w1prep<<<dim3(HID / 64, DIN / 64, NE), 256, 0, stream>>>(W1, gamma, beta, w1t, b1p);
    moe_main<<<dim3((NB / BNB) * NE), 256, 0, stream>>>(xhat, w1t, b1p, w2t, b2,
                                                        wout, logits);
}